// Round 5
// baseline (264.323 us; speedup 1.0000x reference)
//
#include <hip/hip_runtime.h>

typedef __attribute__((ext_vector_type(4))) int int4v;

#define NB_MAX 1024  // partial-max array length

// ---------------- 1) absmax partials over x (no atomics, no memset) --------
__global__ void absmax_partial_kernel(const float* __restrict__ x,
                                      float* __restrict__ partial, int n4) {
  const float4* x4 = (const float4*)x;
  float m = 0.0f;
  for (int i = blockIdx.x * blockDim.x + threadIdx.x; i < n4;
       i += gridDim.x * blockDim.x) {
    float4 v = x4[i];
    m = fmaxf(m, fabsf(v.x));
    m = fmaxf(m, fabsf(v.y));
    m = fmaxf(m, fabsf(v.z));
    m = fmaxf(m, fabsf(v.w));
  }
#pragma unroll
  for (int off = 32; off > 0; off >>= 1)
    m = fmaxf(m, __shfl_down(m, off, 64));
  __shared__ float wmax[4];
  const int wid = threadIdx.x >> 6;
  if ((threadIdx.x & 63) == 0) wmax[wid] = m;
  __syncthreads();
  if (threadIdx.x == 0)
    partial[blockIdx.x] =
        fmaxf(fmaxf(wmax[0], wmax[1]), fmaxf(wmax[2], wmax[3]));
}

// block-wide reduce of the 1024 partials (every block recomputes; ~L2 hits)
__device__ __forceinline__ float reduce_partials(const float* partial) {
  __shared__ float smax;
  float m = 0.0f;
  for (int i = threadIdx.x; i < NB_MAX; i += blockDim.x)
    m = fmaxf(m, partial[i]);
#pragma unroll
  for (int off = 32; off > 0; off >>= 1)
    m = fmaxf(m, __shfl_down(m, off, 64));
  __shared__ float wmax[4];
  const int wid = threadIdx.x >> 6;
  if ((threadIdx.x & 63) == 0) wmax[wid] = m;
  __syncthreads();
  if (threadIdx.x == 0)
    smax = fmaxf(fmaxf(wmax[0], wmax[1]), fmaxf(wmax[2], wmax[3]));
  __syncthreads();
  return smax;
}

// ---------------- 2) fused: quantize x -> int8  AND  pack w -> int8 -------
__global__ void quant_pack_kernel(const float* __restrict__ x,
                                  const int* __restrict__ w,
                                  const float* __restrict__ partial,
                                  float* __restrict__ scale_slot,
                                  int* __restrict__ qx, int* __restrict__ qw,
                                  int nx4, int nw4) {
  const float scale = reduce_partials(partial) / 127.0f;
  const int i = blockIdx.x * blockDim.x + threadIdx.x;
  if (i == 0) *scale_slot = scale;  // benign same-value race if multiple wrote
  if (i < nx4) {
    float4 v = ((const float4*)x)[i];
    // IEEE division + rint (half-to-even) matches jnp.round(t/scale)
    int q0 = (int)fminf(fmaxf(rintf(v.x / scale), -127.0f), 127.0f);
    int q1 = (int)fminf(fmaxf(rintf(v.y / scale), -127.0f), 127.0f);
    int q2 = (int)fminf(fmaxf(rintf(v.z / scale), -127.0f), 127.0f);
    int q3 = (int)fminf(fmaxf(rintf(v.w / scale), -127.0f), 127.0f);
    unsigned int p = (unsigned int)(q0 & 255) |
                     ((unsigned int)(q1 & 255) << 8) |
                     ((unsigned int)(q2 & 255) << 16) |
                     ((unsigned int)(q3 & 255) << 24);
    qx[i] = (int)p;
  }
  if (i < nw4) {
    int4 v = ((const int4*)w)[i];
    unsigned int p = (unsigned int)(v.x & 255) |
                     ((unsigned int)(v.y & 255) << 8) |
                     ((unsigned int)(v.z & 255) << 16) |
                     ((unsigned int)(v.w & 255) << 24);
    qw[i] = (int)p;
  }
}

// ---------------- 3) int8 GEMM: out[t][o] = sum_k A[t][k]*B[o][k] ----------
// 128x128 tile, BK=128 bytes, SINGLE LDS buffer (32 KB) with REGISTER-STAGED
// pipeline: next tile is global_load'ed into VGPRs BEFORE computing on the
// current LDS tile, and ds_write'n after the read-barrier. The vmcnt drain
// thus lands after ~700 cyc of MFMA+ds_read overlap instead of before it
// (round-4 counters: all pipes <40% busy -> drain stall was ~50% of time).
// XOR swizzle (chunk ^= row&7) keeps both ds_write and ds_read conflict-free.
__global__ __launch_bounds__(256) void gemm_i8_kernel(
    const signed char* __restrict__ A,   // [T][K] int8
    const signed char* __restrict__ B,   // [N][K] int8
    const float* __restrict__ bias,
    const float* __restrict__ scale_slot,
    const float* __restrict__ wscale,
    float* __restrict__ out, int K, int N) {
  __shared__ signed char As[128 * 128];
  __shared__ signed char Bs[128 * 128];

  const int tid = threadIdx.x;
  const int lane = tid & 63;
  const int wid = tid >> 6;
  const int row0 = blockIdx.y * 128;
  const int col0 = blockIdx.x * 128;
  const int wm = (wid >> 1) * 64;
  const int wn = (wid & 1) * 64;

  int4v acc[4][4] = {};

  // staging: round t covers rows wid*32 + t*8 + (lane>>3); lane's LDS chunk
  // is lane&7; LDS chunk c of row r holds global chunk c ^ (r&7).
  const int gchunk = ((lane & 7) ^ ((lane >> 3) & 7)) * 16;
  const signed char* gA =
      A + (long)(row0 + wid * 32 + (lane >> 3)) * K + gchunk;
  const signed char* gB =
      B + (long)(col0 + wid * 32 + (lane >> 3)) * K + gchunk;
  const int ldsw = wid * 4096;        // wave's 4 KB stripe (32 rows)
  const long rstride = 8 * (long)K;   // 8 rows per staging round

  // fragment reads: row m = lane&15 (+16i); global chunk s*4 + (lane>>4);
  // LDS chunk = that ^ (row&7) = ^ (lane&7).
  const int q = lane >> 4;
  const int c7 = lane & 7;
  const int frow = (wm + (lane & 15)) * 128;
  const int fbrow = (wn + (lane & 15)) * 128;
  const int fcs0 = ((q ^ c7) << 4);
  const int fcs1 = (((4 + q) ^ c7) << 4);

  int4v rA[4], rB[4];

#define LOAD_TILE(k0)                                      \
  {                                                        \
    _Pragma("unroll") for (int t = 0; t < 4; t++) {        \
      rA[t] = *(const int4v*)(gA + (k0) + t * rstride);    \
      rB[t] = *(const int4v*)(gB + (k0) + t * rstride);    \
    }                                                      \
  }

#define STORE_LDS()                                              \
  {                                                              \
    _Pragma("unroll") for (int t = 0; t < 4; t++) {              \
      *(int4v*)(As + ldsw + t * 1024 + lane * 16) = rA[t];       \
      *(int4v*)(Bs + ldsw + t * 1024 + lane * 16) = rB[t];       \
    }                                                            \
  }

#define COMPUTE()                                                          \
  {                                                                        \
    _Pragma("unroll") for (int s = 0; s < 2; s++) {                        \
      const int ca = (s == 0) ? fcs0 : fcs1;                               \
      int4v a[4], b[4];                                                    \
      _Pragma("unroll") for (int i = 0; i < 4; i++) {                      \
        a[i] = *(const int4v*)(As + frow + i * 16 * 128 + ca);             \
        b[i] = *(const int4v*)(Bs + fbrow + i * 16 * 128 + ca);            \
      }                                                                    \
      _Pragma("unroll") for (int i = 0; i < 4; i++)                        \
          _Pragma("unroll") for (int j = 0; j < 4; j++) acc[i][j] =        \
          __builtin_amdgcn_mfma_i32_16x16x64_i8(a[i], b[j], acc[i][j], 0,  \
                                                0, 0);                     \
    }                                                                      \
  }

  // prologue: tile 0 through registers into LDS
  LOAD_TILE(0)
  STORE_LDS()
  __syncthreads();

  for (int k0 = 128; k0 < K; k0 += 128) {
    LOAD_TILE(k0)   // global loads issue here; vmcnt waited only at STORE_LDS
    COMPUTE()       // overlaps the loads (32 MFMA + 16 ds_read_b128)
    __syncthreads();  // all waves done reading LDS
    STORE_LDS()       // implicit s_waitcnt vmcnt(0) lands here (mostly met)
    __syncthreads();  // writes visible
  }
  COMPUTE()  // last tile
#undef LOAD_TILE
#undef STORE_LDS
#undef COMPUTE

  // epilogue: dequant + bias. C/D: col = lane&15, row = (lane>>4)*4 + reg
  const float s = scale_slot[0] * wscale[0];
  const int orow = row0 + wm + ((lane >> 4) << 2);
  const int ocol0 = col0 + wn + (lane & 15);
#pragma unroll
  for (int j = 0; j < 4; j++) {
    const int c = ocol0 + j * 16;
    const float bv = bias[c];
#pragma unroll
    for (int i = 0; i < 4; i++) {
#pragma unroll
      for (int r = 0; r < 4; r++) {
        out[(long)(orow + i * 16 + r) * N + c] = (float)acc[i][j][r] * s + bv;
      }
    }
  }
}

extern "C" void kernel_launch(void* const* d_in, const int* in_sizes, int n_in,
                              void* d_out, int out_size, void* d_ws,
                              size_t ws_size, hipStream_t stream) {
  const float* x = (const float*)d_in[0];
  const int* w = (const int*)d_in[1];
  const float* wscale = (const float*)d_in[2];
  const float* bias = (const float*)d_in[3];
  float* out = (float*)d_out;

  const int OUT_F = in_sizes[3];
  const int IN_F = in_sizes[1] / OUT_F;
  const int TOKENS = in_sizes[0] / IN_F;

  float* partial = (float*)d_ws;                       // 1024 floats
  float* scale_slot = partial + NB_MAX;                // 1 float
  signed char* qx = (signed char*)d_ws + 8192;
  signed char* qw = qx + (size_t)TOKENS * IN_F;

  const int nx4 = TOKENS * IN_F / 4;
  const int nw4 = OUT_F * IN_F / 4;

  absmax_partial_kernel<<<NB_MAX, 256, 0, stream>>>(x, partial, nx4);

  const int nmax = nx4 > nw4 ? nx4 : nw4;
  quant_pack_kernel<<<(nmax + 255) / 256, 256, 0, stream>>>(
      x, w, partial, scale_slot, (int*)qx, (int*)qw, nx4, nw4);

  dim3 grid(OUT_F / 128, TOKENS / 128);
  gemm_i8_kernel<<<grid, 256, 0, stream>>>(qx, qw, bias, scale_slot, wscale,
                                           out, IN_F, OUT_F);
}